// Round 3
// baseline (4849.109 us; speedup 1.0000x reference)
//
#include <hip/hip_runtime.h>
#include <hip/hip_bf16.h>

// ---------------------------------------------------------------------------
// BasicDGCNN forward, MI355X (gfx950). Inputs f32, output f32.
// Output layout (f32, flat): [0,768) vertex | [768,772) num_vertices |
// [772,776) nvs | [776,1800) gfeat | [1800,..) x_concat [4,8192,224].
//
// Round-15: r14's filter is sound (absmax bit-exact) but two measured
// overheads remained: (1) mid-scan drains (BUF=8, __any per 4-group) fire
// ~every group -> insert1 wave-slots ~500 vs ~100 true inserts; (2) D=64
// demands ~155 VGPRs (xi[64]+dl/il+bfr) vs 128 -> scratch spills (FETCH
// 103MB vs 29MB input). Fix: BUF=TJ=32 -> drain EXACTLY once per tile
// (32 j's can't overflow 32 slots; no mid-scan __any at all); D=64 insert1
// reads the query row from global (L1-hot, identical bits, same fma chain)
// freeing xi[64]. Threshold staleness <= one tile window -> still a strict
// superset; exact-recompute chain byte-identical -> candidate lists
// bit-identical to r12 -> absmax must stay 0.2949219 exactly.
// ---------------------------------------------------------------------------

#define NPTS 8192
#define BATCH 4
#define KNBR 20

typedef _Float16 half8 __attribute__((ext_vector_type(8)));
typedef float f32x4 __attribute__((ext_vector_type(4)));

__device__ __forceinline__ int cswz(int r, int nc) {   // f16-chunk swizzle
    return (nc == 8) ? (r & 7) : ((r >> 1) & 3);
}
__device__ __forceinline__ int dswz(int q) { return (q >> 1) & 7; }

// ===================== KNN phase A: MFMA top-21 per split ==================
// grid (ROWS/128, S); block 128 thr (2 waves). Block owns 128 queries, scans
// its split's 1024 j's in 32-j tiles. Approx dist via CENTERED fp16 MFMA
// (filter), exact f32 recompute+insert for survivors -> bit-exact vs r12.
template <int D, int DK, int RS, int S>
__global__ __launch_bounds__(128) void knn_part_mfma(
    const float* feat, float* xcat) {
    constexpr int TJ  = 32;
    constexpr int BUF = 32;                  // == TJ: one tile can't overflow
    constexpr int JC  = NPTS / S;            // 1024
    constexpr int NC  = DK / 8;              // f16 chunks / row (4 or 8)
    constexpr int KS  = DK / 32;             // MFMA K-steps
    constexpr int DSTR = 32;                 // dist row stride (f32, XOR swz)
    constexpr int RSF = (D % 4 == 0) ? D : 9;  // xjf row stride (f32)
    constexpr bool QG = (D == 64);           // query row via global in drain
    constexpr int REGA = 16384;              // max(xih 128*DK*2, dist 16KB)
    constexpr int OFF_XJF = REGA;
    constexpr int OFF_XJH = OFF_XJF + ((TJ * RSF * 4 + 15) & ~15);
    constexpr int OFF_XXJ = OFF_XJH + TJ * DK * 2;
    constexpr int OFF_SXJ = OFF_XXJ + JC * 4;
    constexpr int OFF_BUF = OFF_SXJ + JC * 4;
    constexpr int OFF_MEA = OFF_BUF + BUF * 128 * 2;
    constexpr int OFF_TMX = OFF_MEA + ((D * 4 + 15) & ~15);
    __shared__ __align__(16) char smem[OFF_TMX + (JC / TJ) * 4];

    float*          dist = (float*)smem;                 // tile phase
    _Float16*       xih  = (_Float16*)smem;              // setup phase only
    float*          xjf  = (float*)(smem + OFF_XJF);     // ORIGINAL f32
    _Float16*       xjh  = (_Float16*)(smem + OFF_XJH);  // centered f16
    float*          xxj  = (float*)(smem + OFF_XXJ);     // exact chains
    float*          sxj  = (float*)(smem + OFF_SXJ);     // centered norms
    unsigned short* bufj = (unsigned short*)(smem + OFF_BUF);
    float*          meanp= (float*)(smem + OFF_MEA);
    float*          tmax = (float*)(smem + OFF_TMX);     // per-tile margin max

    const int tid   = threadIdx.x;
    const int gi    = blockIdx.x * 128 + tid;
    const int s     = blockIdx.y;
    const int b     = gi >> 13;
    const int ib    = gi & (NPTS - 1);
    const int n0b   = (blockIdx.x * 128) & (NPTS - 1);
    const int sbase = s * JC;
    const float* fb = feat + (size_t)b * NPTS * RS;

    const float C1 = 0.001953125f;          // 2^-9  (f16 product bound, 2x)
    const float C2 = 1.52587890625e-05f;    // 2^-16 (f32 chain bound, 4x)

    // ---- xi + xxi: exact chains, identical to round-12 ----
    float xi[D];                // for QG templates: dead after setup
    if (D % 4 == 0) {
        #pragma unroll
        for (int c4 = 0; c4 < D / 4; ++c4) {
            float4 v = *(const float4*)(fb + (size_t)ib * RS + 4 * c4);
            xi[4 * c4] = v.x; xi[4 * c4 + 1] = v.y;
            xi[4 * c4 + 2] = v.z; xi[4 * c4 + 3] = v.w;
        }
    } else {
        #pragma unroll
        for (int c = 0; c < D; ++c) xi[c] = fb[(size_t)ib * RS + c];
    }
    float xxi = 0.f;
    #pragma unroll
    for (int c = 0; c < D; ++c) xxi = fmaf(xi[c], xi[c], xxi);

    // ---- center = block's first query row (any translation is sound) ----
    if (tid < D) meanp[tid] = fb[(size_t)n0b * RS + tid];
    __syncthreads();

    float s_i = 0.f;                        // centered query norm (filter)
    #pragma unroll
    for (int c = 0; c < D; ++c) {
        float d = xi[c] - meanp[c];
        s_i = fmaf(d, d, s_i);
    }
    const float off_i = fmaf(C1, s_i, C2 * xxi) - s_i;

    // ---- stage xih: 128 query rows, CENTERED f16, padded, swizzled ----
    for (int e = tid; e < 128 * NC; e += 128) {
        int r = e / NC, c = e % NC;
        const float* row = fb + (size_t)(n0b + r) * RS;
        half8 h;
        if (D % 8 == 0) {
            float4 v0 = *(const float4*)(row + c * 8);
            float4 v1 = *(const float4*)(row + c * 8 + 4);
            float4 m0 = *(const float4*)(meanp + c * 8);
            float4 m1 = *(const float4*)(meanp + c * 8 + 4);
            h[0] = (_Float16)(v0.x - m0.x); h[1] = (_Float16)(v0.y - m0.y);
            h[2] = (_Float16)(v0.z - m0.z); h[3] = (_Float16)(v0.w - m0.w);
            h[4] = (_Float16)(v1.x - m1.x); h[5] = (_Float16)(v1.y - m1.y);
            h[6] = (_Float16)(v1.z - m1.z); h[7] = (_Float16)(v1.w - m1.w);
        } else {
            #pragma unroll
            for (int t = 0; t < 8; ++t) {
                int dim = c * 8 + t;
                h[t] = (dim < D) ? (_Float16)(row[dim] - meanp[dim])
                                 : (_Float16)0.f;
            }
        }
        *(half8*)(xih + (size_t)r * DK + (c ^ cswz(r, NC)) * 8) = h;
    }

    // ---- xxj (EXACT per-row chains == round-12) + sxj (centered) ----
    for (int r = tid; r < JC; r += 128) {
        const float* row = fb + (size_t)(sbase + r) * RS;
        float sm = 0.f, sc = 0.f;
        if (D % 4 == 0) {
            #pragma unroll
            for (int c4 = 0; c4 < D / 4; ++c4) {
                float4 v = *(const float4*)(row + 4 * c4);
                sm = fmaf(v.x, v.x, sm); sm = fmaf(v.y, v.y, sm);
                sm = fmaf(v.z, v.z, sm); sm = fmaf(v.w, v.w, sm);
                float4 m = *(const float4*)(meanp + 4 * c4);
                float d0 = v.x - m.x, d1 = v.y - m.y;
                float d2 = v.z - m.z, d3 = v.w - m.w;
                sc = fmaf(d0, d0, sc); sc = fmaf(d1, d1, sc);
                sc = fmaf(d2, d2, sc); sc = fmaf(d3, d3, sc);
            }
        } else {
            #pragma unroll
            for (int c = 0; c < D; ++c) {
                float v = row[c];
                sm = fmaf(v, v, sm);
                float d = v - meanp[c];
                sc = fmaf(d, d, sc);
            }
        }
        xxj[r] = sm;
        sxj[r] = sc;
    }
    __syncthreads();

    // ---- B-fragments (this wave's 64 queries), held in registers ----
    const int lane = tid & 63, wid = tid >> 6;
    const int ln = lane & 15, lg = lane >> 4;
    half8 bfr[4][KS];
    #pragma unroll
    for (int qs = 0; qs < 4; ++qs)
        #pragma unroll
        for (int ks = 0; ks < KS; ++ks) {
            int q = wid * 64 + qs * 16 + ln;
            bfr[qs][ks] = *(const half8*)(
                xih + (size_t)q * DK + (((lg + 4 * ks) ^ cswz(q, NC)) * 8));
        }

    // ---- per-tile margin maxima (rotated reads: conflict-free) ----
    if (tid < JC / TJ) {
        float mx = -__builtin_inff();
        for (int r = 0; r < TJ; ++r) {
            int j = tid * TJ + ((r + tid) & (TJ - 1));
            mx = fmaxf(mx, fmaf(C1, sxj[j], C2 * xxj[j]));
        }
        tmax[tid] = mx;
    }

    float dl[21];
    int   il[21];
    #pragma unroll
    for (int t = 0; t < 21; ++t) { dl[t] = __builtin_inff(); il[t] = 0; }
    float thr_t  = __builtin_inff();   // dl[20]+off_i+tmaxcur (tile-stale ok)
    float tmaxcur = 0.f;
    int   cnt = 0;
    int   j0s = 0;

    // exact recompute + strict-< insert (byte-identical chain to round-12);
    // unrolled x2: dd chains independent, insertion order preserved (FIFO).
    auto insert1 = [&](int u) {
        if (u < cnt) {
            int jsp = (int)bufj[u * 128 + tid];
            int jl  = jsp - j0s;
            const float* row = xjf + (size_t)jl * RSF;
            float dot = 0.f;
            if (D % 4 == 0) {
                int fsw = jl & 7;
                const float* qrow = fb + (size_t)ib * RS;
                #pragma unroll
                for (int c4 = 0; c4 < D / 4; ++c4) {
                    float4 v = *(const float4*)(row + ((c4 ^ fsw) * 4));
                    float qx, qy, qz, qw;
                    if constexpr (QG) {     // identical bits, L1-hot
                        float4 q = *(const float4*)(qrow + 4 * c4);
                        qx = q.x; qy = q.y; qz = q.z; qw = q.w;
                    } else {
                        qx = xi[4 * c4 + 0]; qy = xi[4 * c4 + 1];
                        qz = xi[4 * c4 + 2]; qw = xi[4 * c4 + 3];
                    }
                    dot = fmaf(qx, v.x, dot);
                    dot = fmaf(qy, v.y, dot);
                    dot = fmaf(qz, v.z, dot);
                    dot = fmaf(qw, v.w, dot);
                }
            } else {
                #pragma unroll
                for (int c = 0; c < D; ++c) dot = fmaf(xi[c], row[c], dot);
            }
            float dd = __builtin_fmaf(-2.f, dot, xxi + xxj[jsp]);
            if (dd < dl[20]) {            // strict: ties keep earlier j
                dl[20] = dd; il[20] = sbase + jsp;
                #pragma unroll
                for (int t = 20; t > 0; --t) {
                    if (dl[t] < dl[t - 1]) {
                        float td = dl[t]; dl[t] = dl[t - 1]; dl[t - 1] = td;
                        int   ti = il[t]; il[t] = il[t - 1]; il[t - 1] = ti;
                    }
                }
            }
        }
    };
    auto drain = [&]() {
        #pragma unroll 1
        for (int u = 0; __any(u < cnt); u += 2) {
            insert1(u);
            insert1(u + 1);
        }
        cnt = 0;
        thr_t = dl[20] + off_i + tmaxcur;
    };

    #pragma unroll 1
    for (int t0 = 0; t0 < JC; t0 += TJ) {
        j0s = t0;
        __syncthreads();                 // prev tile's drains done; LDS free
        // ---- stage xjf (ORIGINAL f32, swz) + xjh (centered f16, swz) ----
        if (D % 8 == 0) {
            for (int e = tid; e < TJ * NC; e += 128) {
                int r = e / NC, c = e % NC;
                const float* row = fb + (size_t)(sbase + t0 + r) * RS + c * 8;
                float4 v0 = *(const float4*)(row);
                float4 v1 = *(const float4*)(row + 4);
                int fsw = r & 7;
                *(float4*)(xjf + (size_t)r * RSF + (((2 * c)     ^ fsw) * 4)) = v0;
                *(float4*)(xjf + (size_t)r * RSF + (((2 * c + 1) ^ fsw) * 4)) = v1;
                float4 m0 = *(const float4*)(meanp + c * 8);
                float4 m1 = *(const float4*)(meanp + c * 8 + 4);
                half8 h;
                h[0] = (_Float16)(v0.x - m0.x); h[1] = (_Float16)(v0.y - m0.y);
                h[2] = (_Float16)(v0.z - m0.z); h[3] = (_Float16)(v0.w - m0.w);
                h[4] = (_Float16)(v1.x - m1.x); h[5] = (_Float16)(v1.y - m1.y);
                h[6] = (_Float16)(v1.z - m1.z); h[7] = (_Float16)(v1.w - m1.w);
                *(half8*)(xjh + (size_t)r * DK + ((c ^ cswz(r, NC)) * 8)) = h;
            }
        } else {   // D=5: scalar, xjf plain stride-9 (original values)
            for (int e = tid; e < TJ * NC; e += 128) {
                int r = e / NC, c = e % NC;
                const float* row = fb + (size_t)(sbase + t0 + r) * RS;
                half8 h;
                #pragma unroll
                for (int q2 = 0; q2 < 8; ++q2) {
                    int dim = c * 8 + q2;
                    float f = (dim < D) ? row[dim] : 0.f;
                    h[q2] = (dim < D) ? (_Float16)(f - meanp[dim])
                                      : (_Float16)0.f;
                    if (c == 0 && q2 < D) xjf[(size_t)r * RSF + q2] = f;
                }
                *(half8*)(xjh + (size_t)r * DK + ((c ^ cswz(r, NC)) * 8)) = h;
            }
        }
        __syncthreads();
        tmaxcur = tmax[t0 >> 5];
        thr_t   = dl[20] + off_i + tmaxcur;

        // ---- MFMA: dot tiles -> dist stores sv = -2*dot~ ----
        #pragma unroll
        for (int js = 0; js < TJ / 16; ++js) {
            half8 afr[KS];
            #pragma unroll
            for (int ks = 0; ks < KS; ++ks) {
                int jr = js * 16 + ln;
                afr[ks] = *(const half8*)(
                    xjh + (size_t)jr * DK +
                    (((lg + 4 * ks) ^ cswz(jr, NC)) * 8));
            }
            #pragma unroll
            for (int qs = 0; qs < 4; ++qs) {
                f32x4 acc = {0.f, 0.f, 0.f, 0.f};
                #pragma unroll
                for (int ks = 0; ks < KS; ++ks)
                    acc = __builtin_amdgcn_mfma_f32_16x16x32_f16(
                        afr[ks], bfr[qs][ks], acc, 0, 0, 0);
                float4 sv;   // rows of C = j (4 consecutive per lane)
                sv.x = -2.f * acc[0];
                sv.y = -2.f * acc[1];
                sv.z = -2.f * acc[2];
                sv.w = -2.f * acc[3];
                int q  = wid * 64 + qs * 16 + ln;
                int ck = js * 4 + lg;
                *(float4*)(dist + (size_t)q * DSTR + ((ck ^ dswz(q)) * 4)) = sv;
            }
        }
        __syncthreads();

        // ---- scan own row: da2 = sv + s~j < thr -> append (FIFO) ----
        // no mid-scan drains: a 32-j tile cannot overflow BUF=32.
        {
            float* drow = dist + (size_t)tid * DSTR;
            int dsw = dswz(tid);
            #pragma unroll
            for (int c = 0; c < TJ / 4; ++c) {
                float4 sx4 = *(const float4*)(sxj + t0 + c * 4); // broadcast
                float4 sv  = *(const float4*)(drow + ((c ^ dsw) * 4));
                int jb = t0 + c * 4;
                if (sv.x + sx4.x < thr_t) { bufj[cnt * 128 + tid] = (unsigned short)(jb);     ++cnt; }
                if (sv.y + sx4.y < thr_t) { bufj[cnt * 128 + tid] = (unsigned short)(jb + 1); ++cnt; }
                if (sv.z + sx4.z < thr_t) { bufj[cnt * 128 + tid] = (unsigned short)(jb + 2); ++cnt; }
                if (sv.w + sx4.w < thr_t) { bufj[cnt * 128 + tid] = (unsigned short)(jb + 3); ++cnt; }
            }
            drain();   // once per tile; buffered j's need this tile's xjf
        }
    }

    unsigned short* cp =
        (unsigned short*)(xcat + (size_t)gi * 224 + 96) + s * 21;
    #pragma unroll
    for (int t = 0; t < 21; ++t) cp[t] = (unsigned short)il[t];
}

// ===================== KNN phase B: merge S x 21 candidates ================
// Recompute d with the SAME fma ordering as phase A; insert candidates in
// (split asc, stored rank) order with strict < -> stability == jax top_k.
// Drop entry 0 (self).
template <int D, int RS, int S>
__global__ __launch_bounds__(256) void knn_merge(
    const float* feat, const float* xcat, unsigned short* __restrict__ idxout) {
    int gi = blockIdx.x * 256 + threadIdx.x;
    int b  = gi >> 13;
    int ib = gi & (NPTS - 1);
    const float* fb = feat + (size_t)b * NPTS * RS;

    float xi[D];
    if (D % 4 == 0) {
        #pragma unroll
        for (int c4 = 0; c4 < D / 4; ++c4) {
            float4 v = *(const float4*)(fb + (size_t)ib * RS + 4 * c4);
            xi[4 * c4] = v.x; xi[4 * c4 + 1] = v.y;
            xi[4 * c4 + 2] = v.z; xi[4 * c4 + 3] = v.w;
        }
    } else {
        #pragma unroll
        for (int c = 0; c < D; ++c) xi[c] = fb[(size_t)ib * RS + c];
    }
    float xxi = 0.f;
    #pragma unroll
    for (int c = 0; c < D; ++c) xxi = fmaf(xi[c], xi[c], xxi);

    const unsigned short* cp =
        (const unsigned short*)(xcat + (size_t)gi * 224 + 96);

    float dl[21];
    int   il[21];
    #pragma unroll
    for (int t = 0; t < 21; ++t) { dl[t] = __builtin_inff(); il[t] = 0; }

    for (int t = 0; t < S * 21; ++t) {
        int j = ((int)cp[t]) & (NPTS - 1);
        const float* row = fb + (size_t)j * RS;
        float dot = 0.f, xx = 0.f;
        if (D % 4 == 0) {
            #pragma unroll
            for (int c4 = 0; c4 < D / 4; ++c4) {
                float4 v = *(const float4*)(row + 4 * c4);
                dot = fmaf(xi[4 * c4], v.x, dot);     xx = fmaf(v.x, v.x, xx);
                dot = fmaf(xi[4 * c4 + 1], v.y, dot); xx = fmaf(v.y, v.y, xx);
                dot = fmaf(xi[4 * c4 + 2], v.z, dot); xx = fmaf(v.z, v.z, xx);
                dot = fmaf(xi[4 * c4 + 3], v.w, dot); xx = fmaf(v.w, v.w, xx);
            }
        } else {
            #pragma unroll
            for (int c = 0; c < D; ++c) {
                float v = row[c];
                dot = fmaf(xi[c], v, dot);
                xx  = fmaf(v, v, xx);
            }
        }
        float d = __builtin_fmaf(-2.f, dot, xxi + xx);
        if (d < dl[20]) {
            dl[20] = d; il[20] = j;
            #pragma unroll
            for (int u = 20; u > 0; --u) {
                if (dl[u] < dl[u - 1]) {
                    float td = dl[u]; dl[u] = dl[u - 1]; dl[u - 1] = td;
                    int   ti = il[u]; il[u] = il[u - 1]; il[u - 1] = ti;
                }
            }
        }
    }
    unsigned short* op = idxout + (size_t)gi * KNBR;
    #pragma unroll
    for (int t = 1; t < 21; ++t) op[t - 1] = (unsigned short)il[t];
}

// ===================== EdgeConv (fused BN + leaky + max_k) =================
template <int CIN, int RS, int COUT, int OTILE, int P>
__global__ __launch_bounds__(256) void edgeconv_kernel(
    const float* feat, const unsigned short* __restrict__ knn,
    const float* __restrict__ W, const float* __restrict__ g,
    const float* __restrict__ beta, const float* __restrict__ mu,
    const float* __restrict__ var,
    float* outb, int concat_off) {
    __shared__ float diff[P][KNBR][CIN];
    __shared__ float xil[P][CIN];
    __shared__ unsigned short kidx[P * KNBR];
    __shared__ float sl[OTILE], bl[OTILE], ml[OTILE];

    int tid = threadIdx.x;
    int h   = blockIdx.y;
    int n0  = blockIdx.x * P;                 // P divides 8192 -> same batch
    int b   = n0 >> 13;
    const float* fbase = feat + ((size_t)b << 13) * RS;

    for (int e = tid; e < P * CIN; e += 256)
        xil[e / CIN][e % CIN] = feat[(size_t)(n0 + e / CIN) * RS + e % CIN];
    for (int e = tid; e < P * KNBR; e += 256)
        kidx[e] = knn[(size_t)(n0 + e / KNBR) * KNBR + e % KNBR] & (NPTS - 1);
    for (int e = tid; e < OTILE; e += 256) {
        int o = h * OTILE + e;
        sl[e] = g[o] * rsqrtf(var[o] + 1e-5f);
        bl[e] = beta[o];
        ml[e] = mu[o];
    }
    __syncthreads();

    if (CIN % 4 == 0) {
        for (int e = tid; e < P * KNBR * (CIN / 4); e += 256) {
            int r = e / (CIN / 4), c4 = e % (CIN / 4);
            int p = r / KNBR, k = r % KNBR;
            int j = (int)kidx[r];
            float4 v = *(const float4*)(fbase + (size_t)j * RS + 4 * c4);
            diff[p][k][4 * c4 + 0] = v.x - xil[p][4 * c4 + 0];
            diff[p][k][4 * c4 + 1] = v.y - xil[p][4 * c4 + 1];
            diff[p][k][4 * c4 + 2] = v.z - xil[p][4 * c4 + 2];
            diff[p][k][4 * c4 + 3] = v.w - xil[p][4 * c4 + 3];
        }
    } else {
        for (int e = tid; e < P * KNBR * CIN; e += 256) {
            int r = e / CIN, c = e % CIN;
            int pp = r / KNBR, k = r % KNBR;
            int j = (int)kidx[r];
            diff[pp][k][c] = fbase[(size_t)j * RS + c] - xil[pp][c];
        }
    }
    __syncthreads();

    int ol = tid % OTILE, p = tid / OTILE;
    int o  = h * OTILE + ol;

    float wreg[CIN];
    #pragma unroll
    for (int c = 0; c < CIN; ++c) wreg[c] = W[(size_t)o * (2 * CIN) + c];
    float a = 0.f;
    #pragma unroll
    for (int c = 0; c < CIN; ++c) a = fmaf(wreg[c], xil[p][c], a);
    #pragma unroll
    for (int c = 0; c < CIN; ++c) wreg[c] = W[(size_t)o * (2 * CIN) + CIN + c];

    float s = sl[ol], mm = ml[ol], bb = bl[ol];
    float best = -__builtin_inff();
    for (int k = 0; k < KNBR; ++k) {
        float ac0 = a, ac1 = 0.f, ac2 = 0.f, ac3 = 0.f;
        #pragma unroll
        for (int c = 0; c < CIN; ++c) {
            float d = diff[p][k][c];
            if ((c & 3) == 0)      ac0 = fmaf(wreg[c], d, ac0);
            else if ((c & 3) == 1) ac1 = fmaf(wreg[c], d, ac1);
            else if ((c & 3) == 2) ac2 = fmaf(wreg[c], d, ac2);
            else                   ac3 = fmaf(wreg[c], d, ac3);
        }
        float acc = ((ac0 + ac1) + ac2) + ac3;
        float y = (acc - mm) * s + bb;
        y = (y >= 0.f) ? y : 0.2f * y;
        best = fmaxf(best, y);
    }
    outb[(size_t)(n0 + p) * 224 + concat_off + o] = best;
}

// ===================== conv_global: LDS-tiled GEMM + fused max =============
__global__ __launch_bounds__(256) void convglobal_kernel(
    const float* __restrict__ xcat,
    const float* __restrict__ Wg, const float* __restrict__ gg,
    const float* __restrict__ bg, const float* __restrict__ mg,
    const float* __restrict__ vg,
    float* __restrict__ partial) {
    const int KC = 56, PT = 64, OT = 64, ST = 68;   // ST: padded row stride
    __shared__ float flT[KC * ST];                  // [c][p]  15.2 KB
    __shared__ float WlT[KC * ST];                  // [c][o]  15.2 KB
    __shared__ float red[64 * 17];                  //          4.4 KB

    int tid = threadIdx.x;
    int oi  = tid & 15, pi = tid >> 4;
    int o0  = blockIdx.y * OT;
    int n0  = blockIdx.x * PT;                      // 64 | 8192 -> same batch
    int b   = n0 >> 13;
    int pchunk = blockIdx.x & 127;                  // chunk within batch

    float acc[4][4];
    #pragma unroll
    for (int u = 0; u < 4; ++u)
        #pragma unroll
        for (int v = 0; v < 4; ++v) acc[u][v] = 0.f;

    for (int kc = 0; kc < 224; kc += KC) {
        __syncthreads();
        for (int e = tid; e < PT * (KC / 4); e += 256) {
            int p = e / (KC / 4), c4 = e % (KC / 4);
            float4 v = *(const float4*)(xcat + (size_t)(n0 + p) * 224 + kc + 4 * c4);
            flT[(4 * c4 + 0) * ST + p] = v.x;
            flT[(4 * c4 + 1) * ST + p] = v.y;
            flT[(4 * c4 + 2) * ST + p] = v.z;
            flT[(4 * c4 + 3) * ST + p] = v.w;
        }
        for (int e = tid; e < OT * (KC / 4); e += 256) {
            int o = e / (KC / 4), c4 = e % (KC / 4);
            float4 v = *(const float4*)(Wg + (size_t)(o0 + o) * 224 + kc + 4 * c4);
            WlT[(4 * c4 + 0) * ST + o] = v.x;
            WlT[(4 * c4 + 1) * ST + o] = v.y;
            WlT[(4 * c4 + 2) * ST + o] = v.z;
            WlT[(4 * c4 + 3) * ST + o] = v.w;
        }
        __syncthreads();
        #pragma unroll 8
        for (int c = 0; c < KC; ++c) {
            float4 w4 = *(const float4*)(WlT + c * ST + oi * 4);
            float4 f4 = *(const float4*)(flT + c * ST + pi * 4);
            acc[0][0] = fmaf(w4.x, f4.x, acc[0][0]);
            acc[0][1] = fmaf(w4.x, f4.y, acc[0][1]);
            acc[0][2] = fmaf(w4.x, f4.z, acc[0][2]);
            acc[0][3] = fmaf(w4.x, f4.w, acc[0][3]);
            acc[1][0] = fmaf(w4.y, f4.x, acc[1][0]);
            acc[1][1] = fmaf(w4.y, f4.y, acc[1][1]);
            acc[1][2] = fmaf(w4.y, f4.z, acc[1][2]);
            acc[1][3] = fmaf(w4.y, f4.w, acc[1][3]);
            acc[2][0] = fmaf(w4.z, f4.x, acc[2][0]);
            acc[2][1] = fmaf(w4.z, f4.y, acc[2][1]);
            acc[2][2] = fmaf(w4.z, f4.z, acc[2][2]);
            acc[2][3] = fmaf(w4.z, f4.w, acc[2][3]);
            acc[3][0] = fmaf(w4.w, f4.x, acc[3][0]);
            acc[3][1] = fmaf(w4.w, f4.y, acc[3][1]);
            acc[3][2] = fmaf(w4.w, f4.z, acc[3][2]);
            acc[3][3] = fmaf(w4.w, f4.w, acc[3][3]);
        }
    }
    #pragma unroll
    for (int u = 0; u < 4; ++u) {
        int oL = oi * 4 + u, o = o0 + oL;
        float s = gg[o] * rsqrtf(vg[o] + 1e-5f);
        float mm = mg[o], bb = bg[o];
        float best = -__builtin_inff();
        #pragma unroll
        for (int v = 0; v < 4; ++v) {
            float y = (acc[u][v] - mm) * s + bb;
            y = (y >= 0.f) ? y : 0.2f * y;
            best = fmaxf(best, y);
        }
        red[oL * 17 + pi] = best;
    }
    __syncthreads();
    if (tid < 64) {
        float best = -__builtin_inff();
        #pragma unroll
        for (int q = 0; q < 16; ++q) best = fmaxf(best, red[tid * 17 + q]);
        partial[((size_t)(b * 128 + pchunk)) * 256 + o0 + tid] = best;
    }
}

__global__ void reduce_gfeat_kernel(const float* __restrict__ partial,
                                    float* __restrict__ gfeat,
                                    float* __restrict__ outg) {
    int b = blockIdx.x, o = threadIdx.x;
    float best = -__builtin_inff();
    for (int ch = 0; ch < 128; ++ch)
        best = fmaxf(best, partial[((size_t)b * 128 + ch) * 256 + o]);
    gfeat[b * 256 + o] = best;
    outg[b * 256 + o]  = best;
}

// ===================== heads (per-batch block) =============================
__global__ __launch_bounds__(256) void heads_kernel(
    const float* __restrict__ gfeat,
    const float* __restrict__ Wv1, const float* __restrict__ bv1,
    const float* __restrict__ Wv2, const float* __restrict__ bv2,
    const float* __restrict__ Wq1, const float* __restrict__ bq1,
    const float* __restrict__ Wq2, const float* __restrict__ bq2,
    float* __restrict__ out) {
    int b = blockIdx.x, t = threadIdx.x;
    __shared__ float gf[256], h[512], q[64];
    gf[t] = gfeat[b * 256 + t];
    __syncthreads();
    for (int r = t; r < 512; r += 256) {
        float acc = bv1[r];
        for (int c = 0; c < 256; ++c) acc = fmaf(Wv1[r * 256 + c], gf[c], acc);
        h[r] = fmaxf(acc, 0.f);
    }
    __syncthreads();
    if (t < 192) {
        float acc = bv2[t];
        for (int c = 0; c < 512; ++c) acc = fmaf(Wv2[t * 512 + c], h[c], acc);
        out[b * 192 + t] = acc;               // vertex_coords
    } else {
        int r = t - 192;
        if (r < 64) {
            float acc = bq1[r];
            for (int c = 0; c < 256; ++c) acc = fmaf(Wq1[r * 256 + c], gf[c], acc);
            q[r] = fmaxf(acc, 0.f);
        }
    }
    __syncthreads();
    if (t == 0) {
        float acc = bq2[0];
        for (int c = 0; c < 64; ++c) acc = fmaf(Wq2[c], q[c], acc);
        float nv = 1.0f / (1.0f + expf(-acc));
        out[772 + b] = nv;                                       // nvs
        float num = fminf(fmaxf(rintf(nv * 64.0f), 1.0f), 64.0f);
        out[768 + b] = num;                                      // num_vertices
    }
}

// ============================== launch =====================================
extern "C" void kernel_launch(void* const* d_in, const int* in_sizes, int n_in,
                              void* d_out, int out_size, void* d_ws, size_t ws_size,
                              hipStream_t stream) {
    (void)in_sizes; (void)n_in; (void)out_size; (void)ws_size;
    const float* x   = (const float*)d_in[0];
    const float* W1  = (const float*)d_in[1];
    const float* g1  = (const float*)d_in[2];
    const float* b1  = (const float*)d_in[3];
    const float* m1  = (const float*)d_in[4];
    const float* v1  = (const float*)d_in[5];
    const float* W2  = (const float*)d_in[6];
    const float* g2  = (const float*)d_in[7];
    const float* b2  = (const float*)d_in[8];
    const float* m2  = (const float*)d_in[9];
    const float* v2  = (const float*)d_in[10];
    const float* W3  = (const float*)d_in[11];
    const float* g3  = (const float*)d_in[12];
    const float* b3  = (const float*)d_in[13];
    const float* m3  = (const float*)d_in[14];
    const float* v3  = (const float*)d_in[15];
    const float* Wg  = (const float*)d_in[16];
    const float* gg  = (const float*)d_in[17];
    const float* bg  = (const float*)d_in[18];
    const float* mg  = (const float*)d_in[19];
    const float* vg  = (const float*)d_in[20];
    const float* Wv1 = (const float*)d_in[21];
    const float* bv1 = (const float*)d_in[22];
    const float* Wv2 = (const float*)d_in[23];
    const float* bv2 = (const float*)d_in[24];
    const float* Wq1 = (const float*)d_in[25];
    const float* bq1 = (const float*)d_in[26];
    const float* Wq2 = (const float*)d_in[27];
    const float* bq2 = (const float*)d_in[28];

    float* out  = (float*)d_out;
    float* xcat = out + 1800;                    // f32 [4,8192,224]
    char* ws = (char*)d_ws;
    const int ROWS = BATCH * NPTS;   // 32768

    // ws layout (1,310,720 B; part/gft alias idx AFTER it is dead):
    unsigned short* idx  = (unsigned short*)(ws);        // [32768,20] u16
    float*          part = (float*)(ws);                 // [512,256] f32 (alias)
    float*          gft  = (float*)(ws + 524288);        // [4,256]   f32 (alias)

    // ---- EdgeConv 1: 5 -> 32
    knn_part_mfma<5, 32, 5, 8><<<dim3(ROWS / 128, 8), 128, 0, stream>>>(x, xcat);
    knn_merge<5, 5, 8><<<ROWS / 256, 256, 0, stream>>>(x, xcat, idx);
    edgeconv_kernel<5, 5, 32, 32, 8>
        <<<dim3(ROWS / 8, 1), 256, 0, stream>>>(x, idx, W1, g1, b1, m1, v1, xcat, 0);

    // ---- EdgeConv 2: 32 -> 64 (features from xcat[:,0:32))
    knn_part_mfma<32, 32, 224, 8><<<dim3(ROWS / 128, 8), 128, 0, stream>>>(xcat, xcat);
    knn_merge<32, 224, 8><<<ROWS / 256, 256, 0, stream>>>(xcat, xcat, idx);
    edgeconv_kernel<32, 224, 64, 64, 4>
        <<<dim3(ROWS / 4, 1), 256, 0, stream>>>(xcat, idx, W2, g2, b2, m2, v2, xcat, 32);

    // ---- EdgeConv 3: 64 -> 128 (features from xcat[:,32:96))
    knn_part_mfma<64, 64, 224, 8><<<dim3(ROWS / 128, 8), 128, 0, stream>>>(xcat + 32, xcat);
    knn_merge<64, 224, 8><<<ROWS / 256, 256, 0, stream>>>(xcat + 32, xcat, idx);
    edgeconv_kernel<64, 224, 128, 64, 4>
        <<<dim3(ROWS / 4, 2), 256, 0, stream>>>(xcat + 32, idx, W3, g3, b3, m3, v3, xcat, 96);

    // ---- conv_global (224->256) + max over N  (idx dead; part aliases it)
    convglobal_kernel<<<dim3(ROWS / 64, 4), 256, 0, stream>>>(
        xcat, Wg, gg, bg, mg, vg, part);
    reduce_gfeat_kernel<<<BATCH, 256, 0, stream>>>(part, gft, out + 776);

    // ---- heads
    heads_kernel<<<BATCH, 256, 0, stream>>>(
        gft, Wv1, bv1, Wv2, bv2, Wq1, bq1, Wq2, bq2, out);
}

// Round 4
// 4202.252 us; speedup vs baseline: 1.1539x; 1.1539x over previous
//
#include <hip/hip_runtime.h>
#include <hip/hip_bf16.h>

// ---------------------------------------------------------------------------
// BasicDGCNN forward, MI355X (gfx950). Inputs f32, output f32.
// Output layout (f32, flat): [0,768) vertex | [768,772) num_vertices |
// [772,776) nvs | [776,1800) gfeat | [1800,..) x_concat [4,8192,224].
//
// Round-16: r15 regressed for two measured reasons: (a) QG moved the D=64
// query row from VGPRs to divergent global loads inside the drain (VALUBusy
// 61->34% = VMEM stalls); (b) BUF=32 pushed LDS to 45.5KB -> 3 blocks/CU
// (was 4). Fix: xi back in registers for ALL D; __launch_bounds__(128,2)
// raises the VGPR cap to 256 (LDS is the binding occupancy limit at 2
// waves/SIMD, so the extra regs are free -> no scratch spills); BUF=12
// keeps LDS at 40320B (<=40960 -> 4 blocks/CU) with a RARE mid-scan drain
// check (__any(cnt>8), vs r14's cnt>4 which fired constantly). Filter,
// margins, and exact-recompute chain unchanged (bit-exact three rounds
// running) -> absmax must stay 0.2949219 exactly.
// ---------------------------------------------------------------------------

#define NPTS 8192
#define BATCH 4
#define KNBR 20

typedef _Float16 half8 __attribute__((ext_vector_type(8)));
typedef float f32x4 __attribute__((ext_vector_type(4)));

__device__ __forceinline__ int cswz(int r, int nc) {   // f16-chunk swizzle
    return (nc == 8) ? (r & 7) : ((r >> 1) & 3);
}
__device__ __forceinline__ int dswz(int q) { return (q >> 1) & 7; }

// ===================== KNN phase A: MFMA top-21 per split ==================
// grid (ROWS/128, S); block 128 thr (2 waves). Block owns 128 queries, scans
// its split's 1024 j's in 32-j tiles. Approx dist via CENTERED fp16 MFMA
// (filter), exact f32 recompute+insert for survivors -> bit-exact vs r12.
template <int D, int DK, int RS, int S>
__global__ __launch_bounds__(128, 2) void knn_part_mfma(
    const float* feat, float* xcat) {
    constexpr int TJ  = 32;
    constexpr int BUF = 12;                  // 40320B LDS @D=64 -> 4 blk/CU
    constexpr int JC  = NPTS / S;            // 1024
    constexpr int NC  = DK / 8;              // f16 chunks / row (4 or 8)
    constexpr int KS  = DK / 32;             // MFMA K-steps
    constexpr int DSTR = 32;                 // dist row stride (f32, XOR swz)
    constexpr int RSF = (D % 4 == 0) ? D : 9;  // xjf row stride (f32)
    constexpr int REGA = 16384;              // max(xih 128*DK*2, dist 16KB)
    constexpr int OFF_XJF = REGA;
    constexpr int OFF_XJH = OFF_XJF + ((TJ * RSF * 4 + 15) & ~15);
    constexpr int OFF_XXJ = OFF_XJH + TJ * DK * 2;
    constexpr int OFF_SXJ = OFF_XXJ + JC * 4;
    constexpr int OFF_BUF = OFF_SXJ + JC * 4;
    constexpr int OFF_MEA = OFF_BUF + BUF * 128 * 2;
    constexpr int OFF_TMX = OFF_MEA + ((D * 4 + 15) & ~15);
    __shared__ __align__(16) char smem[OFF_TMX + (JC / TJ) * 4];

    float*          dist = (float*)smem;                 // tile phase
    _Float16*       xih  = (_Float16*)smem;              // setup phase only
    float*          xjf  = (float*)(smem + OFF_XJF);     // ORIGINAL f32
    _Float16*       xjh  = (_Float16*)(smem + OFF_XJH);  // centered f16
    float*          xxj  = (float*)(smem + OFF_XXJ);     // exact chains
    float*          sxj  = (float*)(smem + OFF_SXJ);     // centered norms
    unsigned short* bufj = (unsigned short*)(smem + OFF_BUF);
    float*          meanp= (float*)(smem + OFF_MEA);
    float*          tmax = (float*)(smem + OFF_TMX);     // per-tile margin max

    const int tid   = threadIdx.x;
    const int gi    = blockIdx.x * 128 + tid;
    const int s     = blockIdx.y;
    const int b     = gi >> 13;
    const int ib    = gi & (NPTS - 1);
    const int n0b   = (blockIdx.x * 128) & (NPTS - 1);
    const int sbase = s * JC;
    const float* fb = feat + (size_t)b * NPTS * RS;

    const float C1 = 0.001953125f;          // 2^-9  (f16 product bound, 2x)
    const float C2 = 1.52587890625e-05f;    // 2^-16 (f32 chain bound, 4x)

    // ---- xi + xxi: exact chains, identical to round-12 ----
    float xi[D];
    if (D % 4 == 0) {
        #pragma unroll
        for (int c4 = 0; c4 < D / 4; ++c4) {
            float4 v = *(const float4*)(fb + (size_t)ib * RS + 4 * c4);
            xi[4 * c4] = v.x; xi[4 * c4 + 1] = v.y;
            xi[4 * c4 + 2] = v.z; xi[4 * c4 + 3] = v.w;
        }
    } else {
        #pragma unroll
        for (int c = 0; c < D; ++c) xi[c] = fb[(size_t)ib * RS + c];
    }
    float xxi = 0.f;
    #pragma unroll
    for (int c = 0; c < D; ++c) xxi = fmaf(xi[c], xi[c], xxi);

    // ---- center = block's first query row (any translation is sound) ----
    if (tid < D) meanp[tid] = fb[(size_t)n0b * RS + tid];
    __syncthreads();

    float s_i = 0.f;                        // centered query norm (filter)
    #pragma unroll
    for (int c = 0; c < D; ++c) {
        float d = xi[c] - meanp[c];
        s_i = fmaf(d, d, s_i);
    }
    const float off_i = fmaf(C1, s_i, C2 * xxi) - s_i;

    // ---- stage xih: 128 query rows, CENTERED f16, padded, swizzled ----
    for (int e = tid; e < 128 * NC; e += 128) {
        int r = e / NC, c = e % NC;
        const float* row = fb + (size_t)(n0b + r) * RS;
        half8 h;
        if (D % 8 == 0) {
            float4 v0 = *(const float4*)(row + c * 8);
            float4 v1 = *(const float4*)(row + c * 8 + 4);
            float4 m0 = *(const float4*)(meanp + c * 8);
            float4 m1 = *(const float4*)(meanp + c * 8 + 4);
            h[0] = (_Float16)(v0.x - m0.x); h[1] = (_Float16)(v0.y - m0.y);
            h[2] = (_Float16)(v0.z - m0.z); h[3] = (_Float16)(v0.w - m0.w);
            h[4] = (_Float16)(v1.x - m1.x); h[5] = (_Float16)(v1.y - m1.y);
            h[6] = (_Float16)(v1.z - m1.z); h[7] = (_Float16)(v1.w - m1.w);
        } else {
            #pragma unroll
            for (int t = 0; t < 8; ++t) {
                int dim = c * 8 + t;
                h[t] = (dim < D) ? (_Float16)(row[dim] - meanp[dim])
                                 : (_Float16)0.f;
            }
        }
        *(half8*)(xih + (size_t)r * DK + (c ^ cswz(r, NC)) * 8) = h;
    }

    // ---- xxj (EXACT per-row chains == round-12) + sxj (centered) ----
    for (int r = tid; r < JC; r += 128) {
        const float* row = fb + (size_t)(sbase + r) * RS;
        float sm = 0.f, sc = 0.f;
        if (D % 4 == 0) {
            #pragma unroll
            for (int c4 = 0; c4 < D / 4; ++c4) {
                float4 v = *(const float4*)(row + 4 * c4);
                sm = fmaf(v.x, v.x, sm); sm = fmaf(v.y, v.y, sm);
                sm = fmaf(v.z, v.z, sm); sm = fmaf(v.w, v.w, sm);
                float4 m = *(const float4*)(meanp + 4 * c4);
                float d0 = v.x - m.x, d1 = v.y - m.y;
                float d2 = v.z - m.z, d3 = v.w - m.w;
                sc = fmaf(d0, d0, sc); sc = fmaf(d1, d1, sc);
                sc = fmaf(d2, d2, sc); sc = fmaf(d3, d3, sc);
            }
        } else {
            #pragma unroll
            for (int c = 0; c < D; ++c) {
                float v = row[c];
                sm = fmaf(v, v, sm);
                float d = v - meanp[c];
                sc = fmaf(d, d, sc);
            }
        }
        xxj[r] = sm;
        sxj[r] = sc;
    }
    __syncthreads();

    // ---- B-fragments (this wave's 64 queries), held in registers ----
    const int lane = tid & 63, wid = tid >> 6;
    const int ln = lane & 15, lg = lane >> 4;
    half8 bfr[4][KS];
    #pragma unroll
    for (int qs = 0; qs < 4; ++qs)
        #pragma unroll
        for (int ks = 0; ks < KS; ++ks) {
            int q = wid * 64 + qs * 16 + ln;
            bfr[qs][ks] = *(const half8*)(
                xih + (size_t)q * DK + (((lg + 4 * ks) ^ cswz(q, NC)) * 8));
        }

    // ---- per-tile margin maxima (rotated reads: conflict-free) ----
    if (tid < JC / TJ) {
        float mx = -__builtin_inff();
        for (int r = 0; r < TJ; ++r) {
            int j = tid * TJ + ((r + tid) & (TJ - 1));
            mx = fmaxf(mx, fmaf(C1, sxj[j], C2 * xxj[j]));
        }
        tmax[tid] = mx;
    }

    float dl[21];
    int   il[21];
    #pragma unroll
    for (int t = 0; t < 21; ++t) { dl[t] = __builtin_inff(); il[t] = 0; }
    float thr_t  = __builtin_inff();   // dl[20]+off_i+tmaxcur (stale ok)
    float tmaxcur = 0.f;
    int   cnt = 0;
    int   j0s = 0;

    // exact recompute + strict-< insert (byte-identical chain to round-12);
    // unrolled x2: dd chains independent, insertion order preserved (FIFO).
    auto insert1 = [&](int u) {
        if (u < cnt) {
            int jsp = (int)bufj[u * 128 + tid];
            int jl  = jsp - j0s;
            const float* row = xjf + (size_t)jl * RSF;
            float dot = 0.f;
            if (D % 4 == 0) {
                int fsw = jl & 7;
                #pragma unroll
                for (int c4 = 0; c4 < D / 4; ++c4) {
                    float4 v = *(const float4*)(row + ((c4 ^ fsw) * 4));
                    dot = fmaf(xi[4 * c4 + 0], v.x, dot);
                    dot = fmaf(xi[4 * c4 + 1], v.y, dot);
                    dot = fmaf(xi[4 * c4 + 2], v.z, dot);
                    dot = fmaf(xi[4 * c4 + 3], v.w, dot);
                }
            } else {
                #pragma unroll
                for (int c = 0; c < D; ++c) dot = fmaf(xi[c], row[c], dot);
            }
            float dd = __builtin_fmaf(-2.f, dot, xxi + xxj[jsp]);
            if (dd < dl[20]) {            // strict: ties keep earlier j
                dl[20] = dd; il[20] = sbase + jsp;
                #pragma unroll
                for (int t = 20; t > 0; --t) {
                    if (dl[t] < dl[t - 1]) {
                        float td = dl[t]; dl[t] = dl[t - 1]; dl[t - 1] = td;
                        int   ti = il[t]; il[t] = il[t - 1]; il[t - 1] = ti;
                    }
                }
            }
        }
    };
    auto drain = [&]() {
        #pragma unroll 1
        for (int u = 0; __any(u < cnt); u += 2) {
            insert1(u);
            insert1(u + 1);
        }
        cnt = 0;
        thr_t = dl[20] + off_i + tmaxcur;
    };

    #pragma unroll 1
    for (int t0 = 0; t0 < JC; t0 += TJ) {
        j0s = t0;
        __syncthreads();                 // prev tile's drains done; LDS free
        // ---- stage xjf (ORIGINAL f32, swz) + xjh (centered f16, swz) ----
        if (D % 8 == 0) {
            for (int e = tid; e < TJ * NC; e += 128) {
                int r = e / NC, c = e % NC;
                const float* row = fb + (size_t)(sbase + t0 + r) * RS + c * 8;
                float4 v0 = *(const float4*)(row);
                float4 v1 = *(const float4*)(row + 4);
                int fsw = r & 7;
                *(float4*)(xjf + (size_t)r * RSF + (((2 * c)     ^ fsw) * 4)) = v0;
                *(float4*)(xjf + (size_t)r * RSF + (((2 * c + 1) ^ fsw) * 4)) = v1;
                float4 m0 = *(const float4*)(meanp + c * 8);
                float4 m1 = *(const float4*)(meanp + c * 8 + 4);
                half8 h;
                h[0] = (_Float16)(v0.x - m0.x); h[1] = (_Float16)(v0.y - m0.y);
                h[2] = (_Float16)(v0.z - m0.z); h[3] = (_Float16)(v0.w - m0.w);
                h[4] = (_Float16)(v1.x - m1.x); h[5] = (_Float16)(v1.y - m1.y);
                h[6] = (_Float16)(v1.z - m1.z); h[7] = (_Float16)(v1.w - m1.w);
                *(half8*)(xjh + (size_t)r * DK + ((c ^ cswz(r, NC)) * 8)) = h;
            }
        } else {   // D=5: scalar, xjf plain stride-9 (original values)
            for (int e = tid; e < TJ * NC; e += 128) {
                int r = e / NC, c = e % NC;
                const float* row = fb + (size_t)(sbase + t0 + r) * RS;
                half8 h;
                #pragma unroll
                for (int q2 = 0; q2 < 8; ++q2) {
                    int dim = c * 8 + q2;
                    float f = (dim < D) ? row[dim] : 0.f;
                    h[q2] = (dim < D) ? (_Float16)(f - meanp[dim])
                                      : (_Float16)0.f;
                    if (c == 0 && q2 < D) xjf[(size_t)r * RSF + q2] = f;
                }
                *(half8*)(xjh + (size_t)r * DK + ((c ^ cswz(r, NC)) * 8)) = h;
            }
        }
        __syncthreads();
        tmaxcur = tmax[t0 >> 5];
        thr_t   = dl[20] + off_i + tmaxcur;

        // ---- MFMA: dot tiles -> dist stores sv = -2*dot~ ----
        #pragma unroll
        for (int js = 0; js < TJ / 16; ++js) {
            half8 afr[KS];
            #pragma unroll
            for (int ks = 0; ks < KS; ++ks) {
                int jr = js * 16 + ln;
                afr[ks] = *(const half8*)(
                    xjh + (size_t)jr * DK +
                    (((lg + 4 * ks) ^ cswz(jr, NC)) * 8));
            }
            #pragma unroll
            for (int qs = 0; qs < 4; ++qs) {
                f32x4 acc = {0.f, 0.f, 0.f, 0.f};
                #pragma unroll
                for (int ks = 0; ks < KS; ++ks)
                    acc = __builtin_amdgcn_mfma_f32_16x16x32_f16(
                        afr[ks], bfr[qs][ks], acc, 0, 0, 0);
                float4 sv;   // rows of C = j (4 consecutive per lane)
                sv.x = -2.f * acc[0];
                sv.y = -2.f * acc[1];
                sv.z = -2.f * acc[2];
                sv.w = -2.f * acc[3];
                int q  = wid * 64 + qs * 16 + ln;
                int ck = js * 4 + lg;
                *(float4*)(dist + (size_t)q * DSTR + ((ck ^ dswz(q)) * 4)) = sv;
            }
        }
        __syncthreads();

        // ---- scan own row: sv + s~j < thr -> append (FIFO) ----
        // mid-scan drain only when some lane has >8 pending (rare).
        {
            float* drow = dist + (size_t)tid * DSTR;
            int dsw = dswz(tid);
            #pragma unroll 1
            for (int c = 0; c < TJ / 4; ++c) {
                if (__any(cnt > BUF - 4)) drain();
                float4 sx4 = *(const float4*)(sxj + t0 + c * 4); // broadcast
                float4 sv  = *(const float4*)(drow + ((c ^ dsw) * 4));
                int jb = t0 + c * 4;
                if (sv.x + sx4.x < thr_t) { bufj[cnt * 128 + tid] = (unsigned short)(jb);     ++cnt; }
                if (sv.y + sx4.y < thr_t) { bufj[cnt * 128 + tid] = (unsigned short)(jb + 1); ++cnt; }
                if (sv.z + sx4.z < thr_t) { bufj[cnt * 128 + tid] = (unsigned short)(jb + 2); ++cnt; }
                if (sv.w + sx4.w < thr_t) { bufj[cnt * 128 + tid] = (unsigned short)(jb + 3); ++cnt; }
            }
            drain();   // once per tile; buffered j's need this tile's xjf
        }
    }

    unsigned short* cp =
        (unsigned short*)(xcat + (size_t)gi * 224 + 96) + s * 21;
    #pragma unroll
    for (int t = 0; t < 21; ++t) cp[t] = (unsigned short)il[t];
}

// ===================== KNN phase B: merge S x 21 candidates ================
// Recompute d with the SAME fma ordering as phase A; insert candidates in
// (split asc, stored rank) order with strict < -> stability == jax top_k.
// Drop entry 0 (self).
template <int D, int RS, int S>
__global__ __launch_bounds__(256) void knn_merge(
    const float* feat, const float* xcat, unsigned short* __restrict__ idxout) {
    int gi = blockIdx.x * 256 + threadIdx.x;
    int b  = gi >> 13;
    int ib = gi & (NPTS - 1);
    const float* fb = feat + (size_t)b * NPTS * RS;

    float xi[D];
    if (D % 4 == 0) {
        #pragma unroll
        for (int c4 = 0; c4 < D / 4; ++c4) {
            float4 v = *(const float4*)(fb + (size_t)ib * RS + 4 * c4);
            xi[4 * c4] = v.x; xi[4 * c4 + 1] = v.y;
            xi[4 * c4 + 2] = v.z; xi[4 * c4 + 3] = v.w;
        }
    } else {
        #pragma unroll
        for (int c = 0; c < D; ++c) xi[c] = fb[(size_t)ib * RS + c];
    }
    float xxi = 0.f;
    #pragma unroll
    for (int c = 0; c < D; ++c) xxi = fmaf(xi[c], xi[c], xxi);

    const unsigned short* cp =
        (const unsigned short*)(xcat + (size_t)gi * 224 + 96);

    float dl[21];
    int   il[21];
    #pragma unroll
    for (int t = 0; t < 21; ++t) { dl[t] = __builtin_inff(); il[t] = 0; }

    for (int t = 0; t < S * 21; ++t) {
        int j = ((int)cp[t]) & (NPTS - 1);
        const float* row = fb + (size_t)j * RS;
        float dot = 0.f, xx = 0.f;
        if (D % 4 == 0) {
            #pragma unroll
            for (int c4 = 0; c4 < D / 4; ++c4) {
                float4 v = *(const float4*)(row + 4 * c4);
                dot = fmaf(xi[4 * c4], v.x, dot);     xx = fmaf(v.x, v.x, xx);
                dot = fmaf(xi[4 * c4 + 1], v.y, dot); xx = fmaf(v.y, v.y, xx);
                dot = fmaf(xi[4 * c4 + 2], v.z, dot); xx = fmaf(v.z, v.z, xx);
                dot = fmaf(xi[4 * c4 + 3], v.w, dot); xx = fmaf(v.w, v.w, xx);
            }
        } else {
            #pragma unroll
            for (int c = 0; c < D; ++c) {
                float v = row[c];
                dot = fmaf(xi[c], v, dot);
                xx  = fmaf(v, v, xx);
            }
        }
        float d = __builtin_fmaf(-2.f, dot, xxi + xx);
        if (d < dl[20]) {
            dl[20] = d; il[20] = j;
            #pragma unroll
            for (int u = 20; u > 0; --u) {
                if (dl[u] < dl[u - 1]) {
                    float td = dl[u]; dl[u] = dl[u - 1]; dl[u - 1] = td;
                    int   ti = il[u]; il[u] = il[u - 1]; il[u - 1] = ti;
                }
            }
        }
    }
    unsigned short* op = idxout + (size_t)gi * KNBR;
    #pragma unroll
    for (int t = 1; t < 21; ++t) op[t - 1] = (unsigned short)il[t];
}

// ===================== EdgeConv (fused BN + leaky + max_k) =================
template <int CIN, int RS, int COUT, int OTILE, int P>
__global__ __launch_bounds__(256) void edgeconv_kernel(
    const float* feat, const unsigned short* __restrict__ knn,
    const float* __restrict__ W, const float* __restrict__ g,
    const float* __restrict__ beta, const float* __restrict__ mu,
    const float* __restrict__ var,
    float* outb, int concat_off) {
    __shared__ float diff[P][KNBR][CIN];
    __shared__ float xil[P][CIN];
    __shared__ unsigned short kidx[P * KNBR];
    __shared__ float sl[OTILE], bl[OTILE], ml[OTILE];

    int tid = threadIdx.x;
    int h   = blockIdx.y;
    int n0  = blockIdx.x * P;                 // P divides 8192 -> same batch
    int b   = n0 >> 13;
    const float* fbase = feat + ((size_t)b << 13) * RS;

    for (int e = tid; e < P * CIN; e += 256)
        xil[e / CIN][e % CIN] = feat[(size_t)(n0 + e / CIN) * RS + e % CIN];
    for (int e = tid; e < P * KNBR; e += 256)
        kidx[e] = knn[(size_t)(n0 + e / KNBR) * KNBR + e % KNBR] & (NPTS - 1);
    for (int e = tid; e < OTILE; e += 256) {
        int o = h * OTILE + e;
        sl[e] = g[o] * rsqrtf(var[o] + 1e-5f);
        bl[e] = beta[o];
        ml[e] = mu[o];
    }
    __syncthreads();

    if (CIN % 4 == 0) {
        for (int e = tid; e < P * KNBR * (CIN / 4); e += 256) {
            int r = e / (CIN / 4), c4 = e % (CIN / 4);
            int p = r / KNBR, k = r % KNBR;
            int j = (int)kidx[r];
            float4 v = *(const float4*)(fbase + (size_t)j * RS + 4 * c4);
            diff[p][k][4 * c4 + 0] = v.x - xil[p][4 * c4 + 0];
            diff[p][k][4 * c4 + 1] = v.y - xil[p][4 * c4 + 1];
            diff[p][k][4 * c4 + 2] = v.z - xil[p][4 * c4 + 2];
            diff[p][k][4 * c4 + 3] = v.w - xil[p][4 * c4 + 3];
        }
    } else {
        for (int e = tid; e < P * KNBR * CIN; e += 256) {
            int r = e / CIN, c = e % CIN;
            int pp = r / KNBR, k = r % KNBR;
            int j = (int)kidx[r];
            diff[pp][k][c] = fbase[(size_t)j * RS + c] - xil[pp][c];
        }
    }
    __syncthreads();

    int ol = tid % OTILE, p = tid / OTILE;
    int o  = h * OTILE + ol;

    float wreg[CIN];
    #pragma unroll
    for (int c = 0; c < CIN; ++c) wreg[c] = W[(size_t)o * (2 * CIN) + c];
    float a = 0.f;
    #pragma unroll
    for (int c = 0; c < CIN; ++c) a = fmaf(wreg[c], xil[p][c], a);
    #pragma unroll
    for (int c = 0; c < CIN; ++c) wreg[c] = W[(size_t)o * (2 * CIN) + CIN + c];

    float s = sl[ol], mm = ml[ol], bb = bl[ol];
    float best = -__builtin_inff();
    for (int k = 0; k < KNBR; ++k) {
        float ac0 = a, ac1 = 0.f, ac2 = 0.f, ac3 = 0.f;
        #pragma unroll
        for (int c = 0; c < CIN; ++c) {
            float d = diff[p][k][c];
            if ((c & 3) == 0)      ac0 = fmaf(wreg[c], d, ac0);
            else if ((c & 3) == 1) ac1 = fmaf(wreg[c], d, ac1);
            else if ((c & 3) == 2) ac2 = fmaf(wreg[c], d, ac2);
            else                   ac3 = fmaf(wreg[c], d, ac3);
        }
        float acc = ((ac0 + ac1) + ac2) + ac3;
        float y = (acc - mm) * s + bb;
        y = (y >= 0.f) ? y : 0.2f * y;
        best = fmaxf(best, y);
    }
    outb[(size_t)(n0 + p) * 224 + concat_off + o] = best;
}

// ===================== conv_global: LDS-tiled GEMM + fused max =============
__global__ __launch_bounds__(256) void convglobal_kernel(
    const float* __restrict__ xcat,
    const float* __restrict__ Wg, const float* __restrict__ gg,
    const float* __restrict__ bg, const float* __restrict__ mg,
    const float* __restrict__ vg,
    float* __restrict__ partial) {
    const int KC = 56, PT = 64, OT = 64, ST = 68;   // ST: padded row stride
    __shared__ float flT[KC * ST];                  // [c][p]  15.2 KB
    __shared__ float WlT[KC * ST];                  // [c][o]  15.2 KB
    __shared__ float red[64 * 17];                  //          4.4 KB

    int tid = threadIdx.x;
    int oi  = tid & 15, pi = tid >> 4;
    int o0  = blockIdx.y * OT;
    int n0  = blockIdx.x * PT;                      // 64 | 8192 -> same batch
    int b   = n0 >> 13;
    int pchunk = blockIdx.x & 127;                  // chunk within batch

    float acc[4][4];
    #pragma unroll
    for (int u = 0; u < 4; ++u)
        #pragma unroll
        for (int v = 0; v < 4; ++v) acc[u][v] = 0.f;

    for (int kc = 0; kc < 224; kc += KC) {
        __syncthreads();
        for (int e = tid; e < PT * (KC / 4); e += 256) {
            int p = e / (KC / 4), c4 = e % (KC / 4);
            float4 v = *(const float4*)(xcat + (size_t)(n0 + p) * 224 + kc + 4 * c4);
            flT[(4 * c4 + 0) * ST + p] = v.x;
            flT[(4 * c4 + 1) * ST + p] = v.y;
            flT[(4 * c4 + 2) * ST + p] = v.z;
            flT[(4 * c4 + 3) * ST + p] = v.w;
        }
        for (int e = tid; e < OT * (KC / 4); e += 256) {
            int o = e / (KC / 4), c4 = e % (KC / 4);
            float4 v = *(const float4*)(Wg + (size_t)(o0 + o) * 224 + kc + 4 * c4);
            WlT[(4 * c4 + 0) * ST + o] = v.x;
            WlT[(4 * c4 + 1) * ST + o] = v.y;
            WlT[(4 * c4 + 2) * ST + o] = v.z;
            WlT[(4 * c4 + 3) * ST + o] = v.w;
        }
        __syncthreads();
        #pragma unroll 8
        for (int c = 0; c < KC; ++c) {
            float4 w4 = *(const float4*)(WlT + c * ST + oi * 4);
            float4 f4 = *(const float4*)(flT + c * ST + pi * 4);
            acc[0][0] = fmaf(w4.x, f4.x, acc[0][0]);
            acc[0][1] = fmaf(w4.x, f4.y, acc[0][1]);
            acc[0][2] = fmaf(w4.x, f4.z, acc[0][2]);
            acc[0][3] = fmaf(w4.x, f4.w, acc[0][3]);
            acc[1][0] = fmaf(w4.y, f4.x, acc[1][0]);
            acc[1][1] = fmaf(w4.y, f4.y, acc[1][1]);
            acc[1][2] = fmaf(w4.y, f4.z, acc[1][2]);
            acc[1][3] = fmaf(w4.y, f4.w, acc[1][3]);
            acc[2][0] = fmaf(w4.z, f4.x, acc[2][0]);
            acc[2][1] = fmaf(w4.z, f4.y, acc[2][1]);
            acc[2][2] = fmaf(w4.z, f4.z, acc[2][2]);
            acc[2][3] = fmaf(w4.z, f4.w, acc[2][3]);
            acc[3][0] = fmaf(w4.w, f4.x, acc[3][0]);
            acc[3][1] = fmaf(w4.w, f4.y, acc[3][1]);
            acc[3][2] = fmaf(w4.w, f4.z, acc[3][2]);
            acc[3][3] = fmaf(w4.w, f4.w, acc[3][3]);
        }
    }
    #pragma unroll
    for (int u = 0; u < 4; ++u) {
        int oL = oi * 4 + u, o = o0 + oL;
        float s = gg[o] * rsqrtf(vg[o] + 1e-5f);
        float mm = mg[o], bb = bg[o];
        float best = -__builtin_inff();
        #pragma unroll
        for (int v = 0; v < 4; ++v) {
            float y = (acc[u][v] - mm) * s + bb;
            y = (y >= 0.f) ? y : 0.2f * y;
            best = fmaxf(best, y);
        }
        red[oL * 17 + pi] = best;
    }
    __syncthreads();
    if (tid < 64) {
        float best = -__builtin_inff();
        #pragma unroll
        for (int q = 0; q < 16; ++q) best = fmaxf(best, red[tid * 17 + q]);
        partial[((size_t)(b * 128 + pchunk)) * 256 + o0 + tid] = best;
    }
}

__global__ void reduce_gfeat_kernel(const float* __restrict__ partial,
                                    float* __restrict__ gfeat,
                                    float* __restrict__ outg) {
    int b = blockIdx.x, o = threadIdx.x;
    float best = -__builtin_inff();
    for (int ch = 0; ch < 128; ++ch)
        best = fmaxf(best, partial[((size_t)b * 128 + ch) * 256 + o]);
    gfeat[b * 256 + o] = best;
    outg[b * 256 + o]  = best;
}

// ===================== heads (per-batch block) =============================
__global__ __launch_bounds__(256) void heads_kernel(
    const float* __restrict__ gfeat,
    const float* __restrict__ Wv1, const float* __restrict__ bv1,
    const float* __restrict__ Wv2, const float* __restrict__ bv2,
    const float* __restrict__ Wq1, const float* __restrict__ bq1,
    const float* __restrict__ Wq2, const float* __restrict__ bq2,
    float* __restrict__ out) {
    int b = blockIdx.x, t = threadIdx.x;
    __shared__ float gf[256], h[512], q[64];
    gf[t] = gfeat[b * 256 + t];
    __syncthreads();
    for (int r = t; r < 512; r += 256) {
        float acc = bv1[r];
        for (int c = 0; c < 256; ++c) acc = fmaf(Wv1[r * 256 + c], gf[c], acc);
        h[r] = fmaxf(acc, 0.f);
    }
    __syncthreads();
    if (t < 192) {
        float acc = bv2[t];
        for (int c = 0; c < 512; ++c) acc = fmaf(Wv2[t * 512 + c], h[c], acc);
        out[b * 192 + t] = acc;               // vertex_coords
    } else {
        int r = t - 192;
        if (r < 64) {
            float acc = bq1[r];
            for (int c = 0; c < 256; ++c) acc = fmaf(Wq1[r * 256 + c], gf[c], acc);
            q[r] = fmaxf(acc, 0.f);
        }
    }
    __syncthreads();
    if (t == 0) {
        float acc = bq2[0];
        for (int c = 0; c < 64; ++c) acc = fmaf(Wq2[c], q[c], acc);
        float nv = 1.0f / (1.0f + expf(-acc));
        out[772 + b] = nv;                                       // nvs
        float num = fminf(fmaxf(rintf(nv * 64.0f), 1.0f), 64.0f);
        out[768 + b] = num;                                      // num_vertices
    }
}

// ============================== launch =====================================
extern "C" void kernel_launch(void* const* d_in, const int* in_sizes, int n_in,
                              void* d_out, int out_size, void* d_ws, size_t ws_size,
                              hipStream_t stream) {
    (void)in_sizes; (void)n_in; (void)out_size; (void)ws_size;
    const float* x   = (const float*)d_in[0];
    const float* W1  = (const float*)d_in[1];
    const float* g1  = (const float*)d_in[2];
    const float* b1  = (const float*)d_in[3];
    const float* m1  = (const float*)d_in[4];
    const float* v1  = (const float*)d_in[5];
    const float* W2  = (const float*)d_in[6];
    const float* g2  = (const float*)d_in[7];
    const float* b2  = (const float*)d_in[8];
    const float* m2  = (const float*)d_in[9];
    const float* v2  = (const float*)d_in[10];
    const float* W3  = (const float*)d_in[11];
    const float* g3  = (const float*)d_in[12];
    const float* b3  = (const float*)d_in[13];
    const float* m3  = (const float*)d_in[14];
    const float* v3  = (const float*)d_in[15];
    const float* Wg  = (const float*)d_in[16];
    const float* gg  = (const float*)d_in[17];
    const float* bg  = (const float*)d_in[18];
    const float* mg  = (const float*)d_in[19];
    const float* vg  = (const float*)d_in[20];
    const float* Wv1 = (const float*)d_in[21];
    const float* bv1 = (const float*)d_in[22];
    const float* Wv2 = (const float*)d_in[23];
    const float* bv2 = (const float*)d_in[24];
    const float* Wq1 = (const float*)d_in[25];
    const float* bq1 = (const float*)d_in[26];
    const float* Wq2 = (const float*)d_in[27];
    const float* bq2 = (const float*)d_in[28];

    float* out  = (float*)d_out;
    float* xcat = out + 1800;                    // f32 [4,8192,224]
    char* ws = (char*)d_ws;
    const int ROWS = BATCH * NPTS;   // 32768

    // ws layout (1,310,720 B; part/gft alias idx AFTER it is dead):
    unsigned short* idx  = (unsigned short*)(ws);        // [32768,20] u16
    float*          part = (float*)(ws);                 // [512,256] f32 (alias)
    float*          gft  = (float*)(ws + 524288);        // [4,256]   f32 (alias)

    // ---- EdgeConv 1: 5 -> 32
    knn_part_mfma<5, 32, 5, 8><<<dim3(ROWS / 128, 8), 128, 0, stream>>>(x, xcat);
    knn_merge<5, 5, 8><<<ROWS / 256, 256, 0, stream>>>(x, xcat, idx);
    edgeconv_kernel<5, 5, 32, 32, 8>
        <<<dim3(ROWS / 8, 1), 256, 0, stream>>>(x, idx, W1, g1, b1, m1, v1, xcat, 0);

    // ---- EdgeConv 2: 32 -> 64 (features from xcat[:,0:32))
    knn_part_mfma<32, 32, 224, 8><<<dim3(ROWS / 128, 8), 128, 0, stream>>>(xcat, xcat);
    knn_merge<32, 224, 8><<<ROWS / 256, 256, 0, stream>>>(xcat, xcat, idx);
    edgeconv_kernel<32, 224, 64, 64, 4>
        <<<dim3(ROWS / 4, 1), 256, 0, stream>>>(xcat, idx, W2, g2, b2, m2, v2, xcat, 32);

    // ---- EdgeConv 3: 64 -> 128 (features from xcat[:,32:96))
    knn_part_mfma<64, 64, 224, 8><<<dim3(ROWS / 128, 8), 128, 0, stream>>>(xcat + 32, xcat);
    knn_merge<64, 224, 8><<<ROWS / 256, 256, 0, stream>>>(xcat + 32, xcat, idx);
    edgeconv_kernel<64, 224, 128, 64, 4>
        <<<dim3(ROWS / 4, 2), 256, 0, stream>>>(xcat + 32, idx, W3, g3, b3, m3, v3, xcat, 96);

    // ---- conv_global (224->256) + max over N  (idx dead; part aliases it)
    convglobal_kernel<<<dim3(ROWS / 64, 4), 256, 0, stream>>>(
        xcat, Wg, gg, bg, mg, vg, part);
    reduce_gfeat_kernel<<<BATCH, 256, 0, stream>>>(part, gft, out + 776);

    // ---- heads
    heads_kernel<<<BATCH, 256, 0, stream>>>(
        gft, Wv1, bv1, Wv2, bv2, Wq1, bq1, Wq2, bq2, out);
}